// Round 1
// baseline (1001.156 us; speedup 1.0000x reference)
//
#include <hip/hip_runtime.h>
#include <math.h>

#define B_ 64
#define N_ 1025
#define D_ 1024
#define C_ 64
#define HW_ 1024

static constexpr float LN_EPS_F = 1e-5f;

// ---------------------------------------------------------------------------
// K1: fused LayerNorm + gamma/gammax scale + GEMM1 (D->C) + b1
// grid 4100 (65600 rows / 16), block 256. 16 rows per block.
// Phase 1: each wave LNs 4 rows (shuffle reduce, no block sync per row),
//          writes t rows to LDS.
// Phase 2: thread (c=lane, g=wave) computes rows 4g..4g+3, col c.
//          LDS reads are wave-uniform (broadcast, conflict-free);
//          w1 reads are coalesced 256B per instruction, L1/L2-hot.
// ---------------------------------------------------------------------------
__global__ __launch_bounds__(256) void k1_ln_gemm1(
    const float* __restrict__ x, const float* __restrict__ ln_w,
    const float* __restrict__ ln_b, const float* __restrict__ gamma,
    const float* __restrict__ gammax, const float* __restrict__ w1,
    const float* __restrict__ b1, float* __restrict__ y1)
{
    __shared__ float t[16][D_];   // 64 KB
    const int tid  = threadIdx.x;
    const int lane = tid & 63;
    const int wv   = tid >> 6;
    const int base = blockIdx.x * 16;

    // ---- Phase 1: LayerNorm + scale, 4 rows per wave ----
    for (int j = 0; j < 4; ++j) {
        const int i = wv * 4 + j;
        const int r = base + i;              // global row in [0, 65600)
        const int b = r / N_;
        const int n = r - b * N_;
        const float* xrow = x + (size_t)n * (B_ * D_) + (size_t)b * D_;

        float4 v[4];
        float s = 0.f, sq = 0.f;
        #pragma unroll
        for (int q = 0; q < 4; ++q) {
            v[q] = *(const float4*)(xrow + q * 256 + lane * 4);
            s  += v[q].x + v[q].y + v[q].z + v[q].w;
            sq += v[q].x * v[q].x + v[q].y * v[q].y
                + v[q].z * v[q].z + v[q].w * v[q].w;
        }
        #pragma unroll
        for (int off = 32; off > 0; off >>= 1) {
            s  += __shfl_xor(s,  off, 64);
            sq += __shfl_xor(sq, off, 64);
        }
        const float mu  = s * (1.0f / D_);
        const float var = sq * (1.0f / D_) - mu * mu;
        const float rs  = rsqrtf(var + LN_EPS_F);

        #pragma unroll
        for (int q = 0; q < 4; ++q) {
            const int d = q * 256 + lane * 4;
            float4 lw = *(const float4*)(ln_w + d);
            float4 lb = *(const float4*)(ln_b + d);
            float4 gm = *(const float4*)(gamma + d);
            float4 gx = *(const float4*)(gammax + d);
            float4 o;
            o.x = ((v[q].x - mu) * rs * lw.x + lb.x) * gm.x + v[q].x * gx.x;
            o.y = ((v[q].y - mu) * rs * lw.y + lb.y) * gm.y + v[q].y * gx.y;
            o.z = ((v[q].z - mu) * rs * lw.z + lb.z) * gm.z + v[q].z * gx.z;
            o.w = ((v[q].w - mu) * rs * lw.w + lb.w) * gm.w + v[q].w * gx.w;
            *(float4*)&t[i][d] = o;
        }
    }
    __syncthreads();

    // ---- Phase 2: GEMM (16 rows x 64 cols) ----
    const int c = lane;
    const float* tr0 = t[wv * 4 + 0];
    const float* tr1 = t[wv * 4 + 1];
    const float* tr2 = t[wv * 4 + 2];
    const float* tr3 = t[wv * 4 + 3];
    const float* w1c = w1 + c;

    float acc0 = 0.f, acc1 = 0.f, acc2 = 0.f, acc3 = 0.f;
    for (int d = 0; d < D_; d += 4) {
        const float wa = w1c[(d + 0) * C_];
        const float wb = w1c[(d + 1) * C_];
        const float wc = w1c[(d + 2) * C_];
        const float wd = w1c[(d + 3) * C_];
        float4 t0 = *(const float4*)(tr0 + d);
        float4 t1 = *(const float4*)(tr1 + d);
        float4 t2 = *(const float4*)(tr2 + d);
        float4 t3 = *(const float4*)(tr3 + d);
        acc0 += t0.x * wa + t0.y * wb + t0.z * wc + t0.w * wd;
        acc1 += t1.x * wa + t1.y * wb + t1.z * wc + t1.w * wd;
        acc2 += t2.x * wa + t2.y * wb + t2.z * wc + t2.w * wd;
        acc3 += t3.x * wa + t3.y * wb + t3.z * wc + t3.w * wd;
    }
    const float bb = b1[c];
    y1[(size_t)(base + wv * 4 + 0) * C_ + c] = acc0 + bb;
    y1[(size_t)(base + wv * 4 + 1) * C_ + c] = acc1 + bb;
    y1[(size_t)(base + wv * 4 + 2) * C_ + c] = acc2 + bb;
    y1[(size_t)(base + wv * 4 + 3) * C_ + c] = acc3 + bb;
}

// ---------------------------------------------------------------------------
// K2: depthwise conv. The 3 convs are linear -> fold into ONE 7x7 kernel:
//     K7 = (dw7 + pad(dw5) + pad(dw3)) / 3, bias = (b3+b5+b7)/3.
// Output: sp2[b][c][p] = conv7(img)[p] + img[p]  (identity residual).
// grid 4096 (B*C), block 256; one 32x32 image per block in LDS.
// ---------------------------------------------------------------------------
__global__ __launch_bounds__(256) void k2_dwconv(
    const float* __restrict__ y1,
    const float* __restrict__ dw3_w, const float* __restrict__ dw3_b,
    const float* __restrict__ dw5_w, const float* __restrict__ dw5_b,
    const float* __restrict__ dw7_w, const float* __restrict__ dw7_b,
    float* __restrict__ sp2)
{
    __shared__ float img[HW_];
    __shared__ float k7[49];
    const int b   = blockIdx.x >> 6;
    const int c   = blockIdx.x & 63;
    const int tid = threadIdx.x;

    #pragma unroll
    for (int q = 0; q < 4; ++q) {
        const int p = tid + q * 256;
        img[p] = y1[(size_t)(b * N_ + 1 + p) * C_ + c];
    }
    if (tid < 49) {
        const int di = tid / 7, dj = tid % 7;
        float v = dw7_w[c * 49 + tid];
        if (di >= 1 && di <= 5 && dj >= 1 && dj <= 5)
            v += dw5_w[c * 25 + (di - 1) * 5 + (dj - 1)];
        if (di >= 2 && di <= 4 && dj >= 2 && dj <= 4)
            v += dw3_w[c * 9 + (di - 2) * 3 + (dj - 2)];
        k7[tid] = v * (1.0f / 3.0f);
    }
    __syncthreads();

    const float bias = (dw3_b[c] + dw5_b[c] + dw7_b[c]) * (1.0f / 3.0f);
    #pragma unroll
    for (int q = 0; q < 4; ++q) {
        const int p = tid + q * 256;
        const int i = p >> 5, j0 = p & 31;
        float acc = bias;
        #pragma unroll
        for (int ki = 0; ki < 7; ++ki) {
            const int ii = i + ki - 3;
            if ((unsigned)ii < 32u) {
                #pragma unroll
                for (int kj = 0; kj < 7; ++kj) {
                    const int jj = j0 + kj - 3;
                    if ((unsigned)jj < 32u)
                        acc += img[ii * 32 + jj] * k7[ki * 7 + kj];
                }
            }
        }
        sp2[(size_t)blockIdx.x * HW_ + p] = acc + img[p];
    }
}

// ---------------------------------------------------------------------------
// K3: 1x1 proj (C x C matvec) + residual + exact GELU + repack to (B,N,C).
// One wave per row; lane = output channel. Matvec via __shfl broadcast of v;
// proj_w rows live in L1 (16 KB). n==0 (cls) path is wave-uniform.
// grid 16400 (65600/4), block 256.
// ---------------------------------------------------------------------------
__global__ __launch_bounds__(256) void k3_proj_gelu(
    const float* __restrict__ y1, const float* __restrict__ sp2,
    const float* __restrict__ proj_w, const float* __restrict__ proj_b,
    float* __restrict__ g)
{
    const int tid  = threadIdx.x;
    const int lane = tid & 63;
    const int wv   = tid >> 6;
    const int r = blockIdx.x * 4 + wv;   // row in [0, 65600)
    const int b = r / N_;
    const int n = r - b * N_;

    float v;
    if (n == 0)
        v = y1[(size_t)r * C_ + lane];
    else
        v = sp2[((size_t)b * C_ + lane) * HW_ + (n - 1)];

    float acc = proj_b[lane];
    const float* pw = proj_w + lane * C_;
    #pragma unroll
    for (int cc = 0; cc < C_; ++cc)
        acc += pw[cc] * __shfl(v, cc, 64);

    const float o  = (n == 0) ? v : (v + acc);
    const float ge = 0.5f * o * (1.0f + erff(o * 0.70710678118654752f));
    g[(size_t)r * C_ + lane] = ge;
}

// ---------------------------------------------------------------------------
// K4: GEMM2 (C->D) + b2 + identity residual + transpose to (N,B,D).
// grid 4100, block 256; 16 rows per block. g rows staged in LDS (4 KB);
// w2 read as float4 (coalesced 1KB/instr, L2-hot, ~1 GB total);
// x read / out write coalesced float4.
// ---------------------------------------------------------------------------
__global__ __launch_bounds__(256) void k4_gemm2(
    const float* __restrict__ g, const float* __restrict__ w2,
    const float* __restrict__ b2, const float* __restrict__ x,
    float* __restrict__ out)
{
    __shared__ float gs[16][C_];
    const int tid  = threadIdx.x;
    const int base = blockIdx.x * 16;

    ((float4*)&gs[0][0])[tid] = *(const float4*)(g + (size_t)base * C_ + tid * 4);
    __syncthreads();

    const int d = tid * 4;
    float4 acc[16];
    #pragma unroll
    for (int i = 0; i < 16; ++i) acc[i] = make_float4(0.f, 0.f, 0.f, 0.f);

    for (int cb = 0; cb < C_; cb += 4) {
        float4 w0 = *(const float4*)(w2 + (size_t)(cb + 0) * D_ + d);
        float4 w1v = *(const float4*)(w2 + (size_t)(cb + 1) * D_ + d);
        float4 w2v = *(const float4*)(w2 + (size_t)(cb + 2) * D_ + d);
        float4 w3v = *(const float4*)(w2 + (size_t)(cb + 3) * D_ + d);
        #pragma unroll
        for (int i = 0; i < 16; ++i) {
            float4 gv = *(const float4*)&gs[i][cb];   // wave-uniform: broadcast
            acc[i].x += gv.x * w0.x + gv.y * w1v.x + gv.z * w2v.x + gv.w * w3v.x;
            acc[i].y += gv.x * w0.y + gv.y * w1v.y + gv.z * w2v.y + gv.w * w3v.y;
            acc[i].z += gv.x * w0.z + gv.y * w1v.z + gv.z * w2v.z + gv.w * w3v.z;
            acc[i].w += gv.x * w0.w + gv.y * w1v.w + gv.z * w2v.w + gv.w * w3v.w;
        }
    }

    const float4 bv = *(const float4*)(b2 + d);
    #pragma unroll
    for (int i = 0; i < 16; ++i) {
        const int r = base + i;
        const int b = r / N_;
        const int n = r - b * N_;
        const size_t idx = (size_t)n * (B_ * D_) + (size_t)b * D_ + d;
        float4 xv = *(const float4*)(x + idx);
        float4 o;
        o.x = xv.x + acc[i].x + bv.x;
        o.y = xv.y + acc[i].y + bv.y;
        o.z = xv.z + acc[i].z + bv.z;
        o.w = xv.w + acc[i].w + bv.w;
        *(float4*)(out + idx) = o;
    }
}

// ---------------------------------------------------------------------------
extern "C" void kernel_launch(void* const* d_in, const int* in_sizes, int n_in,
                              void* d_out, int out_size, void* d_ws, size_t ws_size,
                              hipStream_t stream)
{
    const float* x      = (const float*)d_in[0];
    const float* ln_w   = (const float*)d_in[1];
    const float* ln_b   = (const float*)d_in[2];
    const float* gamma  = (const float*)d_in[3];
    const float* gammax = (const float*)d_in[4];
    const float* w1     = (const float*)d_in[5];
    const float* b1     = (const float*)d_in[6];
    const float* w2     = (const float*)d_in[7];
    const float* b2     = (const float*)d_in[8];
    const float* dw3_w  = (const float*)d_in[9];
    const float* dw3_b  = (const float*)d_in[10];
    const float* dw5_w  = (const float*)d_in[11];
    const float* dw5_b  = (const float*)d_in[12];
    const float* dw7_w  = (const float*)d_in[13];
    const float* dw7_b  = (const float*)d_in[14];
    const float* proj_w = (const float*)d_in[15];
    const float* proj_b = (const float*)d_in[16];
    float* out = (float*)d_out;

    // workspace: y1 (B*N*C) | sp2 (B*C*HW) | g (B*N*C)  ~= 50.4 MB
    float* y1  = (float*)d_ws;
    float* sp2 = y1 + (size_t)B_ * N_ * C_;
    float* gbf = sp2 + (size_t)B_ * C_ * HW_;

    k1_ln_gemm1<<<4100, 256, 0, stream>>>(x, ln_w, ln_b, gamma, gammax, w1, b1, y1);
    k2_dwconv<<<4096, 256, 0, stream>>>(y1, dw3_w, dw3_b, dw5_w, dw5_b,
                                        dw7_w, dw7_b, sp2);
    k3_proj_gelu<<<16400, 256, 0, stream>>>(y1, sp2, proj_w, proj_b, gbf);
    k4_gemm2<<<4100, 256, 0, stream>>>(gbf, w2, b2, x, out);
}